// Round 6
// baseline (552.488 us; speedup 1.0000x reference)
//
#include <hip/hip_runtime.h>
#include <hip/hip_fp16.h>

#define FIN 256
#define FH  64
#define SCAN_BLK 1024
#define NCHUNK 8

typedef float f4v __attribute__((ext_vector_type(4)));
typedef float f2v __attribute__((ext_vector_type(2)));

// ---------------- degree ----------------

__global__ __launch_bounds__(256) void deg_kernel(const int* __restrict__ rows,
                                                  unsigned* __restrict__ deg, int E) {
    int e = blockIdx.x * 256 + threadIdx.x;
    if (e < E) atomicAdd(&deg[rows[e]], 1u);
}

// ---------------- scan: per-block scan of deg -> rowptr (block-local) + block totals ----------------

__global__ __launch_bounds__(256) void scan_block_kernel(const unsigned* __restrict__ deg,
                                                         int* __restrict__ rowptr,
                                                         int* __restrict__ blocksums, int N) {
    __shared__ int wsum[4];
    const int t = threadIdx.x;
    const int base = blockIdx.x * SCAN_BLK + t * 4;
    int d0 = 0, d1 = 0, d2 = 0, d3 = 0;
    if (base + 0 < N) d0 = (int)deg[base + 0];
    if (base + 1 < N) d1 = (int)deg[base + 1];
    if (base + 2 < N) d2 = (int)deg[base + 2];
    if (base + 3 < N) d3 = (int)deg[base + 3];
    const int tot = d0 + d1 + d2 + d3;
    const int lane = t & 63, wv = t >> 6;
    int inc = tot;
#pragma unroll
    for (int off = 1; off < 64; off <<= 1) {
        int v = __shfl_up(inc, off, 64);
        if (lane >= off) inc += v;
    }
    if (lane == 63) wsum[wv] = inc;
    __syncthreads();
    int woff = 0;
    for (int w = 0; w < wv; ++w) woff += wsum[w];
    const int ex = woff + inc - tot;   // exclusive prefix of this thread within block
    if (base + 0 < N) rowptr[base + 0] = ex;
    if (base + 1 < N) rowptr[base + 1] = ex + d0;
    if (base + 2 < N) rowptr[base + 2] = ex + d0 + d1;
    if (base + 3 < N) rowptr[base + 3] = ex + d0 + d1 + d2;
    if (t == 255) blocksums[blockIdx.x] = woff + inc;   // block TOTAL (unscanned)
}

// ---------------- scan_add: add cross-block prefix; also emit cursor and dis ----------------

__global__ __launch_bounds__(256) void scan_add_kernel(int* __restrict__ rowptr,
                                                       int* __restrict__ cursor,
                                                       const unsigned* __restrict__ deg,
                                                       float* __restrict__ dis,
                                                       const int* __restrict__ blocksums,
                                                       int nb, int N, int E) {
    __shared__ int pre;
    const int t = threadIdx.x;
    const int i0 = blockIdx.x * 256;
    const int c0 = i0 / SCAN_BLK;
    if (t == 0) {
        int s = 0;
        for (int k = 0; k < c0; ++k) s += blocksums[k];
        pre = s;
    }
    __syncthreads();
    int i = i0 + t;
    if (i < N) {
        int v = rowptr[i] + pre;
        rowptr[i] = v;
        cursor[i] = v;
        unsigned d = deg[i];
        dis[i] = d ? 1.0f / sqrtf((float)d) : 0.0f;
    }
    if (i == 0) rowptr[N] = E;
}

// ---------------- counting-sort edges into CSR col array, row-range chunked ----------------
// inv[e] = CSR position of edge e (sequential write in e); pos-decode writes P in CSR
// order, permute kernel maps back.

__global__ __launch_bounds__(256) void scatter_edges_kernel(const int* __restrict__ rows,
                                                            const int* __restrict__ cols,
                                                            int* __restrict__ cursor,
                                                            int* __restrict__ colOut,
                                                            int* __restrict__ inv,
                                                            float chunk_scale, int E) {
    const int chunk = blockIdx.x & (NCHUNK - 1);
    const int eb = blockIdx.x >> 3;
    int e = eb * 256 + threadIdx.x;
    if (e >= E) return;
    int r = rows[e];
    int rc = (int)((float)r * chunk_scale);
    rc = rc > (NCHUNK - 1) ? (NCHUNK - 1) : rc;
    if (rc == chunk) {
        int p = atomicAdd(&cursor[r], 1);
        colOut[p] = cols[e];
        inv[e] = p;
    }
}

// ---------------- GEMM1: h16[N][64] = fp16( (x[N][256] @ W[256][64] + b) * dis[r] ) ----------------
// x loads are non-temporal: 102 MB single-use stream must not evict gather tables.

__global__ __launch_bounds__(256) void gemm1_kernel(const float* __restrict__ x,
                                                    const float* __restrict__ W,
                                                    const float* __restrict__ b,
                                                    const float* __restrict__ dis,
                                                    __half2* __restrict__ outh, int N) {
    __shared__ float xs[32][132];
    __shared__ float ws[32][64];
    const int t = threadIdx.x;
    const int rb = blockIdx.x * 128;
    const int rg = t >> 3, cg = t & 7;
    const int r0 = rg * 4, c0 = cg * 8;
    float acc[4][8];
#pragma unroll
    for (int i = 0; i < 4; ++i)
#pragma unroll
        for (int j = 0; j < 8; ++j) acc[i][j] = 0.f;

    const f4v* x4 = (const f4v*)x;
    const int kk = (t & 7) * 4;
    const int rloc = t >> 3;

    for (int k0 = 0; k0 < FIN; k0 += 32) {
        __syncthreads();
        {
            const float4* w4 = (const float4*)(W + k0 * 64);
            float4* wl = (float4*)&ws[0][0];
            wl[t]       = w4[t];
            wl[t + 256] = w4[t + 256];
        }
#pragma unroll
        for (int p = 0; p < 4; ++p) {
            int r = rloc + p * 32;
            int gr = rb + r; if (gr >= N) gr = N - 1;
            f4v v = __builtin_nontemporal_load(&x4[gr * 64 + (k0 >> 2) + (t & 7)]);
            xs[kk + 0][r] = v.x; xs[kk + 1][r] = v.y;
            xs[kk + 2][r] = v.z; xs[kk + 3][r] = v.w;
        }
        __syncthreads();
#pragma unroll
        for (int k = 0; k < 32; ++k) {
            float4 xa = *(const float4*)&xs[k][r0];
            float4 wa = *(const float4*)&ws[k][c0];
            float4 wb = *(const float4*)&ws[k][c0 + 4];
            float xr[4] = {xa.x, xa.y, xa.z, xa.w};
            float wr[8] = {wa.x, wa.y, wa.z, wa.w, wb.x, wb.y, wb.z, wb.w};
#pragma unroll
            for (int i = 0; i < 4; ++i)
#pragma unroll
                for (int j = 0; j < 8; ++j) acc[i][j] = fmaf(xr[i], wr[j], acc[i][j]);
        }
    }
    float bias[8];
#pragma unroll
    for (int j = 0; j < 8; ++j) bias[j] = b[c0 + j];
#pragma unroll
    for (int i = 0; i < 4; ++i) {
        int gr = rb + r0 + i;
        if (gr < N) {
            float d = dis[gr];
            __half2 o[4];
            o[0] = __floats2half2_rn((acc[i][0] + bias[0]) * d, (acc[i][1] + bias[1]) * d);
            o[1] = __floats2half2_rn((acc[i][2] + bias[2]) * d, (acc[i][3] + bias[3]) * d);
            o[2] = __floats2half2_rn((acc[i][4] + bias[4]) * d, (acc[i][5] + bias[5]) * d);
            o[3] = __floats2half2_rn((acc[i][6] + bias[6]) * d, (acc[i][7] + bias[7]) * d);
            *(uint4*)&outh[gr * 32 + (c0 >> 1)] = *(uint4*)o;   // h16 cached: gather table
        }
    }
}

// ---------------- FUSED gather1 + gemm2 ----------------
// Per row r: agg = sum_{c in N(r)} h16[c]; v = relu(agg*dis[r]); h2[r] = fp16((v@W2+b2)*dis[r]).
// Half-wave (32 lanes) per row, lane owns 2 features. W2 staged in LDS (16 KB) per block;
// matvec is 32 iters of shfl-broadcast + 2 LDS float2 reads + 4 FMA (2-way bank alias = free).
// Kills the 25.6 MB agg intermediate and the gemm2 dispatch; matvec VALU hides under
// gather miss latency (fabric-bound kernel, VALUBusy ~25%).

__global__ __launch_bounds__(256) void gather_mm_kernel(const int* __restrict__ rowptr,
                                                        const int* __restrict__ cols,
                                                        const __half2* __restrict__ h2v,
                                                        const float* __restrict__ dis,
                                                        const float* __restrict__ W2,
                                                        const float* __restrict__ b2,
                                                        __half2* __restrict__ outh, int N) {
    __shared__ float ws[64][64];
    const int t = threadIdx.x;
    {   // stage W2 (64x64 fp32); barrier BEFORE any early return
        const float4* w4 = (const float4*)W2;
        float4* wl = (float4*)&ws[0][0];
#pragma unroll
        for (int p = 0; p < 4; ++p) wl[p * 256 + t] = w4[p * 256 + t];
    }
    __syncthreads();

    int r = blockIdx.x * 8 + (t >> 5);
    if (r >= N) return;                 // safe: no barriers after this point
    const int l32 = t & 31;
    const int rowbase = t & 32;         // shfl base of this half-wave within the wave
    int s = rowptr[r], e = rowptr[r + 1];
    float2 acc[8];
#pragma unroll
    for (int u = 0; u < 8; ++u) { acc[u].x = 0.f; acc[u].y = 0.f; }
    for (int base = s; base < e; base += 32) {
        int n = e - base; if (n > 32) n = 32;
        int idx = (l32 < n) ? cols[base + l32] : 0;
        int j = 0;
        for (; j + 15 < n; j += 16) {
            __half2 tv[16];
#pragma unroll
            for (int u = 0; u < 16; ++u) {
                int c = __shfl(idx, rowbase + j + u);
                tv[u] = h2v[(size_t)c * 32 + l32];
            }
#pragma unroll
            for (int u = 0; u < 16; ++u) {
                float2 f = __half22float2(tv[u]);
                acc[u & 7].x += f.x; acc[u & 7].y += f.y;
            }
        }
        for (; j + 3 < n; j += 4) {
            __half2 tv[4];
#pragma unroll
            for (int u = 0; u < 4; ++u) {
                int c = __shfl(idx, rowbase + j + u);
                tv[u] = h2v[(size_t)c * 32 + l32];
            }
#pragma unroll
            for (int u = 0; u < 4; ++u) {
                float2 f = __half22float2(tv[u]);
                acc[u].x += f.x; acc[u].y += f.y;
            }
        }
        for (; j < n; ++j) {
            int c = __shfl(idx, rowbase + j);
            float2 f = __half22float2(h2v[(size_t)c * 32 + l32]);
            acc[0].x += f.x; acc[0].y += f.y;
        }
    }
    float2 v;
    v.x = ((acc[0].x + acc[1].x) + (acc[2].x + acc[3].x)) + ((acc[4].x + acc[5].x) + (acc[6].x + acc[7].x));
    v.y = ((acc[0].y + acc[1].y) + (acc[2].y + acc[3].y)) + ((acc[4].y + acc[5].y) + (acc[6].y + acc[7].y));
    const float dr = dis[r];
    v.x = fmaxf(v.x * dr, 0.f);
    v.y = fmaxf(v.y * dr, 0.f);
    // matvec: o[j] = sum_k v_k W2[k][j], lane owns j = 2*l32, 2*l32+1
    float2 o; o.x = 0.f; o.y = 0.f;
#pragma unroll 8
    for (int kk = 0; kk < 32; ++kk) {
        float vx = __shfl(v.x, rowbase + kk);
        float vy = __shfl(v.y, rowbase + kk);
        float2 w0 = *(const float2*)&ws[2 * kk][2 * l32];
        float2 w1 = *(const float2*)&ws[2 * kk + 1][2 * l32];
        o.x = fmaf(vx, w0.x, o.x); o.x = fmaf(vy, w1.x, o.x);
        o.y = fmaf(vx, w0.y, o.y); o.y = fmaf(vy, w1.y, o.y);
    }
    float2 bb = *(const float2*)&b2[2 * l32];
    o.x = (o.x + bb.x) * dr;
    o.y = (o.y + bb.y) * dr;
    outh[(size_t)r * 32 + l32] = __float22half2_rn(o);   // h2_16 cached: next gather table
}

// ---------------- gather2: z16[r] = fp16( dis[r] * sum_{c} h2_16[c] ) ----------------

__global__ __launch_bounds__(256) void gather_z_kernel(const int* __restrict__ rowptr,
                                                       const int* __restrict__ cols,
                                                       const __half2* __restrict__ h2v,
                                                       const float* __restrict__ dscale,
                                                       __half2* __restrict__ outh, int N) {
    int r = blockIdx.x * 8 + (threadIdx.x >> 5);
    int l32 = threadIdx.x & 31;
    if (r >= N) return;
    const int rowbase = threadIdx.x & 32;
    int s = rowptr[r], e = rowptr[r + 1];
    float2 acc[8];
#pragma unroll
    for (int u = 0; u < 8; ++u) { acc[u].x = 0.f; acc[u].y = 0.f; }
    for (int base = s; base < e; base += 32) {
        int n = e - base; if (n > 32) n = 32;
        int idx = (l32 < n) ? cols[base + l32] : 0;
        int j = 0;
        for (; j + 15 < n; j += 16) {
            __half2 tv[16];
#pragma unroll
            for (int u = 0; u < 16; ++u) {
                int c = __shfl(idx, rowbase + j + u);
                tv[u] = h2v[(size_t)c * 32 + l32];
            }
#pragma unroll
            for (int u = 0; u < 16; ++u) {
                float2 f = __half22float2(tv[u]);
                acc[u & 7].x += f.x; acc[u & 7].y += f.y;
            }
        }
        for (; j + 3 < n; j += 4) {
            __half2 tv[4];
#pragma unroll
            for (int u = 0; u < 4; ++u) {
                int c = __shfl(idx, rowbase + j + u);
                tv[u] = h2v[(size_t)c * 32 + l32];
            }
#pragma unroll
            for (int u = 0; u < 4; ++u) {
                float2 f = __half22float2(tv[u]);
                acc[u].x += f.x; acc[u].y += f.y;
            }
        }
        for (; j < n; ++j) {
            int c = __shfl(idx, rowbase + j);
            float2 f = __half22float2(h2v[(size_t)c * 32 + l32]);
            acc[0].x += f.x; acc[0].y += f.y;
        }
    }
    float2 v;
    v.x = ((acc[0].x + acc[1].x) + (acc[2].x + acc[3].x)) + ((acc[4].x + acc[5].x) + (acc[6].x + acc[7].x));
    v.y = ((acc[0].y + acc[1].y) + (acc[2].y + acc[3].y)) + ((acc[4].y + acc[5].y) + (acc[6].y + acc[7].y));
    float d = dscale[r]; v.x *= d; v.y *= d;
    outh[(size_t)r * 32 + l32] = __float22half2_rn(v);    // z16 cached: decode table
}

// ---------------- fused decode over fp16 z ----------------
// pos: P[p] written SEQUENTIALLY in CSR order; neg: sequential NT writes.
// All shfls full-half-wave-active.

__device__ __forceinline__ float dot8h(float4 A, float4 B) {
    union { float4 f; __half2 h[4]; } ua, ub;
    ua.f = A; ub.f = B;
    float s = 0.f;
#pragma unroll
    for (int k = 0; k < 4; ++k) {
        float2 fa = __half22float2(ua.h[k]);
        float2 fb = __half22float2(ub.h[k]);
        s = fmaf(fa.x, fb.x, s);
        s = fmaf(fa.y, fb.y, s);
    }
    return s;
}

__global__ __launch_bounds__(256) void decode16_kernel(const int* __restrict__ rowptr,
                                                       const int* __restrict__ cols,
                                                       const int* __restrict__ ne,
                                                       const float4* __restrict__ zf4,
                                                       float* __restrict__ P,
                                                       float* __restrict__ outp,
                                                       int N, int negB, int Ep, int En) {
    const int t = threadIdx.x;
    const int l8 = t & 7;

    if ((int)blockIdx.x < negB) {
        // ----- negative edges: 32 groups x 8 edges per block -----
        const int g = t >> 3;             // 0..31
        const int base = blockIdx.x * 256;
        int a[8], b[8];
        bool v[8];
#pragma unroll
        for (int q = 0; q < 8; ++q) {
            int e = base + q * 32 + g;
            v[q] = e < En;
            a[q] = 0; b[q] = 0;
            if (v[q]) { a[q] = ne[e]; b[q] = ne[En + e]; }
        }
        float4 va[8], vb[8];
#pragma unroll
        for (int q = 0; q < 8; ++q) {
            va[q] = zf4[(size_t)a[q] * 8 + l8];
            vb[q] = zf4[(size_t)b[q] * 8 + l8];
        }
#pragma unroll
        for (int q = 0; q < 8; ++q) {
            float p = dot8h(va[q], vb[q]);
            p += __shfl_xor(p, 4);
            p += __shfl_xor(p, 2);
            p += __shfl_xor(p, 1);
            int e = base + q * 32 + g;
            if (v[q] && l8 == 0) __builtin_nontemporal_store(p, &outp[Ep + e]);
        }
    } else {
        // ----- positive edges via CSR: sequential P write -----
        int r = (blockIdx.x - negB) * 8 + (t >> 5);
        if (r >= N) return;
        const int l32 = t & 31;
        const int rowbase = t & 32;       // shfl base of this half-wave
        const int g4 = (t >> 3) & 3;      // 0..3 (8-lane group within half-wave)
        int s = rowptr[r], e = rowptr[r + 1];
        if (s == e) return;
        float zr8[8];
        {
            union { float4 f; __half2 h[4]; } uz;
            uz.f = zf4[(size_t)r * 8 + l8];
#pragma unroll
            for (int k = 0; k < 4; ++k) {
                float2 f = __half22float2(uz.h[k]);
                zr8[2 * k] = f.x; zr8[2 * k + 1] = f.y;
            }
        }
        for (int base = s; base < e; base += 32) {
            int n = e - base; if (n > 32) n = 32;
            int idx = (l32 < n) ? cols[base + l32] : 0;
            for (int j = 0; j < n; j += 8) {
                int pos0 = j + g4, pos1 = j + 4 + g4;
                bool a0 = pos0 < n, a1 = pos1 < n;
                int c0 = __shfl(idx, rowbase + (a0 ? pos0 : 0));
                int c1 = __shfl(idx, rowbase + (a1 ? pos1 : 0));
                float4 v0 = zf4[(size_t)c0 * 8 + l8];
                float4 v1 = zf4[(size_t)c1 * 8 + l8];
                union { float4 f; __half2 h[4]; } u0, u1;
                u0.f = v0; u1.f = v1;
                float p0 = 0.f, p1 = 0.f;
#pragma unroll
                for (int k = 0; k < 4; ++k) {
                    float2 f0 = __half22float2(u0.h[k]);
                    float2 f1 = __half22float2(u1.h[k]);
                    p0 = fmaf(zr8[2 * k], f0.x, p0); p0 = fmaf(zr8[2 * k + 1], f0.y, p0);
                    p1 = fmaf(zr8[2 * k], f1.x, p1); p1 = fmaf(zr8[2 * k + 1], f1.y, p1);
                }
                p0 += __shfl_xor(p0, 4); p0 += __shfl_xor(p0, 2); p0 += __shfl_xor(p0, 1);
                p1 += __shfl_xor(p1, 4); p1 += __shfl_xor(p1, 2); p1 += __shfl_xor(p1, 1);
                if (l8 == 0) {
                    if (a0) P[base + pos0] = p0;
                    if (a1) P[base + pos1] = p1;
                }
            }
        }
    }
}

// ---------------- permute: out[e] = P[inv[e]] (seq inv NT read, gather L2-resident P, seq NT write) --

__global__ __launch_bounds__(256) void permute_kernel(const float* __restrict__ P,
                                                      const int* __restrict__ inv,
                                                      float* __restrict__ out, int E) {
    int e = blockIdx.x * 256 + threadIdx.x;
    if (e < E) {
        int p = __builtin_nontemporal_load(&inv[e]);
        __builtin_nontemporal_store(P[p], &out[e]);
    }
}

// ---------------- launch ----------------

extern "C" void kernel_launch(void* const* d_in, const int* in_sizes, int n_in,
                              void* d_out, int out_size, void* d_ws, size_t ws_size,
                              hipStream_t stream) {
    const float* x  = (const float*)d_in[0];
    const int*   pe = (const int*)d_in[1];
    const int*   ne = (const int*)d_in[2];
    const float* W1 = (const float*)d_in[3];
    const float* b1 = (const float*)d_in[4];
    const float* W2 = (const float*)d_in[5];
    const float* b2 = (const float*)d_in[6];
    float* outp = (float*)d_out;

    const int N  = in_sizes[0] / FIN;
    const int Ep = in_sizes[1] / 2;
    const int En = in_sizes[2] / 2;

    char* w = (char*)d_ws;
    size_t off = 0;
    auto alloc = [&](size_t bytes) {
        void* p = w + off;
        off = (off + bytes + 255) & ~(size_t)255;
        return p;
    };
    unsigned* deg   = (unsigned*)alloc((size_t)N * 4);
    float* dis      = (float*)alloc((size_t)N * 4);
    int* rowptr     = (int*)alloc((size_t)(N + 1) * 4);
    int* cursor     = (int*)alloc((size_t)N * 4);
    int* blocksums  = (int*)alloc(((size_t)N / SCAN_BLK + 2) * 4);
    int* colsorted  = (int*)alloc((size_t)Ep * 4);
    int* inv        = (int*)alloc((size_t)Ep * 4);
    __half2* A16    = (__half2*)alloc((size_t)N * 64 * 2);   // h16, then z16
    __half2* B16    = (__half2*)alloc((size_t)N * 64 * 2);   // h2_16 (fused out)
    float* P        = (float*)alloc((size_t)Ep * 4);         // pos decode buffer

    const int nscan = (N + SCAN_BLK - 1) / SCAN_BLK;
    const int nEdgeBlocks = (Ep + 255) / 256;

    hipMemsetAsync(deg, 0, (size_t)N * 4, stream);

    // CSR build (pos edges)
    deg_kernel<<<nEdgeBlocks, 256, 0, stream>>>(pe, deg, Ep);
    scan_block_kernel<<<nscan, 256, 0, stream>>>(deg, rowptr, blocksums, N);
    scan_add_kernel<<<(N + 255) / 256, 256, 0, stream>>>(rowptr, cursor, deg, dis,
                                                         blocksums, nscan, N, Ep);
    scatter_edges_kernel<<<nEdgeBlocks * NCHUNK, 256, 0, stream>>>(
        pe, pe + Ep, cursor, colsorted, inv, (float)NCHUNK / (float)N, Ep);
    // layer 1: gemm1 -> h16 (fp16)
    gemm1_kernel<<<(N + 127) / 128, 256, 0, stream>>>(x, W1, b1, dis, A16, N);
    // fused gather1+gemm2: h16 gather -> relu*dis -> @W2+b2 -> *dis -> h2_16
    gather_mm_kernel<<<(N + 7) / 8, 256, 0, stream>>>(rowptr, colsorted, A16, dis,
                                                      W2, b2, B16, N);
    // gather2: h2_16 gather -> *dis -> z16 (overwrites h16, which is dead)
    __half2* z16 = A16;
    gather_z_kernel<<<(N + 7) / 8, 256, 0, stream>>>(rowptr, colsorted, B16, dis, z16, N);
    // decode: pos -> sequential P (CSR order), neg -> direct NT; then permute pos back
    const int negB = (En + 255) / 256;
    const int posB = (N + 7) / 8;
    decode16_kernel<<<negB + posB, 256, 0, stream>>>(rowptr, colsorted, ne,
                                                     (const float4*)z16, P, outp,
                                                     N, negB, Ep, En);
    permute_kernel<<<(Ep + 255) / 256, 256, 0, stream>>>(P, inv, outp, Ep);
}

// Round 8
// 510.023 us; speedup vs baseline: 1.0833x; 1.0833x over previous
//
#include <hip/hip_runtime.h>
#include <hip/hip_fp16.h>

#define FIN 256
#define FH  64
#define SCAN_BLK 1024
#define NCHUNK 8

// ---------------- degree ----------------

__global__ __launch_bounds__(256) void deg_kernel(const int* __restrict__ rows,
                                                  unsigned* __restrict__ deg, int E) {
    int e = blockIdx.x * 256 + threadIdx.x;
    if (e < E) atomicAdd(&deg[rows[e]], 1u);
}

// ---------------- scan: per-block scan of deg -> rowptr (block-local) + block totals ----------------

__global__ __launch_bounds__(256) void scan_block_kernel(const unsigned* __restrict__ deg,
                                                         int* __restrict__ rowptr,
                                                         int* __restrict__ blocksums, int N) {
    __shared__ int wsum[4];
    const int t = threadIdx.x;
    const int base = blockIdx.x * SCAN_BLK + t * 4;
    int d0 = 0, d1 = 0, d2 = 0, d3 = 0;
    if (base + 0 < N) d0 = (int)deg[base + 0];
    if (base + 1 < N) d1 = (int)deg[base + 1];
    if (base + 2 < N) d2 = (int)deg[base + 2];
    if (base + 3 < N) d3 = (int)deg[base + 3];
    const int tot = d0 + d1 + d2 + d3;
    const int lane = t & 63, wv = t >> 6;
    int inc = tot;
#pragma unroll
    for (int off = 1; off < 64; off <<= 1) {
        int v = __shfl_up(inc, off, 64);
        if (lane >= off) inc += v;
    }
    if (lane == 63) wsum[wv] = inc;
    __syncthreads();
    int woff = 0;
    for (int w = 0; w < wv; ++w) woff += wsum[w];
    const int ex = woff + inc - tot;   // exclusive prefix of this thread within block
    if (base + 0 < N) rowptr[base + 0] = ex;
    if (base + 1 < N) rowptr[base + 1] = ex + d0;
    if (base + 2 < N) rowptr[base + 2] = ex + d0 + d1;
    if (base + 3 < N) rowptr[base + 3] = ex + d0 + d1 + d2;
    if (t == 255) blocksums[blockIdx.x] = woff + inc;   // block TOTAL (unscanned)
}

// ---------------- scan_add: add cross-block prefix; also emit cursor and dis ----------------

__global__ __launch_bounds__(256) void scan_add_kernel(int* __restrict__ rowptr,
                                                       int* __restrict__ cursor,
                                                       const unsigned* __restrict__ deg,
                                                       float* __restrict__ dis,
                                                       const int* __restrict__ blocksums,
                                                       int nb, int N, int E) {
    __shared__ int pre;
    const int t = threadIdx.x;
    const int i0 = blockIdx.x * 256;
    const int c0 = i0 / SCAN_BLK;
    if (t == 0) {
        int s = 0;
        for (int k = 0; k < c0; ++k) s += blocksums[k];
        pre = s;
    }
    __syncthreads();
    int i = i0 + t;
    if (i < N) {
        int v = rowptr[i] + pre;
        rowptr[i] = v;
        cursor[i] = v;
        unsigned d = deg[i];
        dis[i] = d ? 1.0f / sqrtf((float)d) : 0.0f;
    }
    if (i == 0) rowptr[N] = E;
}

// ---------------- counting-sort edges into CSR col array, row-range chunked ----------------
// einv[p] = original edge index of CSR slot p: pos-decode scatters final results directly.

__global__ __launch_bounds__(256) void scatter_edges_kernel(const int* __restrict__ rows,
                                                            const int* __restrict__ cols,
                                                            int* __restrict__ cursor,
                                                            int* __restrict__ colOut,
                                                            int* __restrict__ einv,
                                                            float chunk_scale, int E) {
    const int chunk = blockIdx.x & (NCHUNK - 1);
    const int eb = blockIdx.x >> 3;
    int e = eb * 256 + threadIdx.x;
    if (e >= E) return;
    int r = rows[e];
    int rc = (int)((float)r * chunk_scale);
    rc = rc > (NCHUNK - 1) ? (NCHUNK - 1) : rc;
    if (rc == chunk) {
        int p = atomicAdd(&cursor[r], 1);
        colOut[p] = cols[e];
        einv[p] = e;
    }
}

// ---------------- GEMM1: h16[N][64] = fp16( (x[N][256] @ W[256][64] + b) * dis[r] ) ----------------

__global__ __launch_bounds__(256) void gemm1_kernel(const float* __restrict__ x,
                                                    const float* __restrict__ W,
                                                    const float* __restrict__ b,
                                                    const float* __restrict__ dis,
                                                    __half2* __restrict__ outh, int N) {
    __shared__ float xs[32][132];
    __shared__ float ws[32][64];
    const int t = threadIdx.x;
    const int rb = blockIdx.x * 128;
    const int rg = t >> 3, cg = t & 7;
    const int r0 = rg * 4, c0 = cg * 8;
    float acc[4][8];
#pragma unroll
    for (int i = 0; i < 4; ++i)
#pragma unroll
        for (int j = 0; j < 8; ++j) acc[i][j] = 0.f;

    const float4* x4 = (const float4*)x;
    const int kk = (t & 7) * 4;
    const int rloc = t >> 3;

    for (int k0 = 0; k0 < FIN; k0 += 32) {
        __syncthreads();
        {
            const float4* w4 = (const float4*)(W + k0 * 64);
            float4* wl = (float4*)&ws[0][0];
            wl[t]       = w4[t];
            wl[t + 256] = w4[t + 256];
        }
#pragma unroll
        for (int p = 0; p < 4; ++p) {
            int r = rloc + p * 32;
            int gr = rb + r; if (gr >= N) gr = N - 1;
            float4 v = x4[gr * 64 + (k0 >> 2) + (t & 7)];
            xs[kk + 0][r] = v.x; xs[kk + 1][r] = v.y;
            xs[kk + 2][r] = v.z; xs[kk + 3][r] = v.w;
        }
        __syncthreads();
#pragma unroll
        for (int k = 0; k < 32; ++k) {
            float4 xa = *(const float4*)&xs[k][r0];
            float4 wa = *(const float4*)&ws[k][c0];
            float4 wb = *(const float4*)&ws[k][c0 + 4];
            float xr[4] = {xa.x, xa.y, xa.z, xa.w};
            float wr[8] = {wa.x, wa.y, wa.z, wa.w, wb.x, wb.y, wb.z, wb.w};
#pragma unroll
            for (int i = 0; i < 4; ++i)
#pragma unroll
                for (int j = 0; j < 8; ++j) acc[i][j] = fmaf(xr[i], wr[j], acc[i][j]);
        }
    }
    float bias[8];
#pragma unroll
    for (int j = 0; j < 8; ++j) bias[j] = b[c0 + j];
#pragma unroll
    for (int i = 0; i < 4; ++i) {
        int gr = rb + r0 + i;
        if (gr < N) {
            float d = dis[gr];
            __half2 o[4];
            o[0] = __floats2half2_rn((acc[i][0] + bias[0]) * d, (acc[i][1] + bias[1]) * d);
            o[1] = __floats2half2_rn((acc[i][2] + bias[2]) * d, (acc[i][3] + bias[3]) * d);
            o[2] = __floats2half2_rn((acc[i][4] + bias[4]) * d, (acc[i][5] + bias[5]) * d);
            o[3] = __floats2half2_rn((acc[i][6] + bias[6]) * d, (acc[i][7] + bias[7]) * d);
            *(uint4*)&outh[gr * 32 + (c0 >> 1)] = *(uint4*)o;
        }
    }
}

// ---------------- CSR gather over fp16 rows, decode-style ----------------
// Half-wave (32 lanes) per row, split into 4x 8-lane groups. Each lane loads a FULL
// 16-B float4 (8 halves) per neighbor (decode16's proven per-row rate is 2x the
// 4-B-per-lane layout). Group g handles neighbors j+g and j+4+g per step (2 loads
// in flight/lane). Cross-group partials summed via shfl_xor(8/16) at the end.
// Output: fp32 agg row (tohalf=0) or fp16 z row scaled by dscale (tohalf=1).

__global__ __launch_bounds__(256) void gather16_kernel(const int* __restrict__ rowptr,
                                                       const int* __restrict__ cols,
                                                       const float4* __restrict__ h4,
                                                       const float* __restrict__ dscale,
                                                       float* __restrict__ outf,
                                                       __half2* __restrict__ outh,
                                                       int N, int tohalf) {
    const int t = threadIdx.x;
    int r = blockIdx.x * 8 + (t >> 5);
    if (r >= N) return;
    const int l32 = t & 31;
    const int l8 = t & 7;
    const int g4 = (t >> 3) & 3;        // 0..3: 8-lane group within half-wave
    const int rowbase = t & 32;         // shfl base of this half-wave within the wave
    int s = rowptr[r], e = rowptr[r + 1];

    float2 acc[4];
#pragma unroll
    for (int k = 0; k < 4; ++k) { acc[k].x = 0.f; acc[k].y = 0.f; }

    for (int base = s; base < e; base += 32) {
        int n = e - base; if (n > 32) n = 32;
        int idx = (l32 < n) ? cols[base + l32] : 0;
        for (int j = 0; j < n; j += 8) {
            int pos0 = j + g4, pos1 = j + 4 + g4;
            bool a0 = pos0 < n, a1 = pos1 < n;
            int c0 = __shfl(idx, rowbase + (a0 ? pos0 : 0));
            int c1 = __shfl(idx, rowbase + (a1 ? pos1 : 0));
            float4 v0 = h4[(size_t)c0 * 8 + l8];
            float4 v1 = h4[(size_t)c1 * 8 + l8];
            union { float4 f; __half2 h[4]; } u0, u1;
            u0.f = v0; u1.f = v1;
            if (a0) {
#pragma unroll
                for (int k = 0; k < 4; ++k) {
                    float2 f = __half22float2(u0.h[k]);
                    acc[k].x += f.x; acc[k].y += f.y;
                }
            }
            if (a1) {
#pragma unroll
                for (int k = 0; k < 4; ++k) {
                    float2 f = __half22float2(u1.h[k]);
                    acc[k].x += f.x; acc[k].y += f.y;
                }
            }
        }
    }
    // sum the 4 groups' partials (lanes with equal l8 across g4)
#pragma unroll
    for (int k = 0; k < 4; ++k) {
        acc[k].x += __shfl_xor(acc[k].x, 8);
        acc[k].y += __shfl_xor(acc[k].y, 8);
        acc[k].x += __shfl_xor(acc[k].x, 16);
        acc[k].y += __shfl_xor(acc[k].y, 16);
    }
    if (g4 == 0) {
        if (tohalf) {
            float d = dscale[r];
            __half2 o[4];
#pragma unroll
            for (int k = 0; k < 4; ++k)
                o[k] = __floats2half2_rn(acc[k].x * d, acc[k].y * d);
            *(uint4*)&outh[(size_t)r * 32 + l8 * 4] = *(uint4*)o;
        } else {
            float4 o0, o1;
            o0.x = acc[0].x; o0.y = acc[0].y; o0.z = acc[1].x; o0.w = acc[1].y;
            o1.x = acc[2].x; o1.y = acc[2].y; o1.z = acc[3].x; o1.w = acc[3].y;
            *(float4*)&outf[(size_t)r * 64 + l8 * 8]     = o0;
            *(float4*)&outf[(size_t)r * 64 + l8 * 8 + 4] = o1;
        }
    }
}

// ---------------- GEMM2: reads fp32 agg, writes fp16 (dis-applied) ----------------

__global__ __launch_bounds__(256) void gemm2_kernel(const float* __restrict__ agg,
                                                    const float* __restrict__ dis,
                                                    const float* __restrict__ W,
                                                    const float* __restrict__ b,
                                                    __half2* __restrict__ outh, int N) {
    __shared__ float xs[64][132];
    __shared__ float ws[64][64];
    const int t = threadIdx.x;
    const int rb = blockIdx.x * 128;
    {
        const float4* w4 = (const float4*)W;
        float4* wl = (float4*)&ws[0][0];
#pragma unroll
        for (int p = 0; p < 4; ++p) wl[p * 256 + t] = w4[p * 256 + t];
    }
    {
        const float4* a4 = (const float4*)agg;
        const int c4 = (t & 15) * 4;
        const int rloc = t >> 4;
#pragma unroll
        for (int p = 0; p < 8; ++p) {
            int r = rloc + p * 16;
            int gr = rb + r; if (gr >= N) gr = N - 1;
            float d = dis[gr];
            float4 v = a4[gr * 16 + (t & 15)];
            xs[c4 + 0][r] = fmaxf(v.x * d, 0.f);
            xs[c4 + 1][r] = fmaxf(v.y * d, 0.f);
            xs[c4 + 2][r] = fmaxf(v.z * d, 0.f);
            xs[c4 + 3][r] = fmaxf(v.w * d, 0.f);
        }
    }
    __syncthreads();
    const int rg = t >> 3, cg = t & 7;
    const int r0 = rg * 4, c0 = cg * 8;
    float acc[4][8];
#pragma unroll
    for (int i = 0; i < 4; ++i)
#pragma unroll
        for (int j = 0; j < 8; ++j) acc[i][j] = 0.f;
#pragma unroll 16
    for (int k = 0; k < 64; ++k) {
        float4 xa = *(const float4*)&xs[k][r0];
        float4 wa = *(const float4*)&ws[k][c0];
        float4 wb = *(const float4*)&ws[k][c0 + 4];
        float xr[4] = {xa.x, xa.y, xa.z, xa.w};
        float wr[8] = {wa.x, wa.y, wa.z, wa.w, wb.x, wb.y, wb.z, wb.w};
#pragma unroll
        for (int i = 0; i < 4; ++i)
#pragma unroll
            for (int j = 0; j < 8; ++j) acc[i][j] = fmaf(xr[i], wr[j], acc[i][j]);
    }
    float bias[8];
#pragma unroll
    for (int j = 0; j < 8; ++j) bias[j] = b[c0 + j];
#pragma unroll
    for (int i = 0; i < 4; ++i) {
        int gr = rb + r0 + i;
        if (gr < N) {
            float d = dis[gr];
            __half2 o[4];
            o[0] = __floats2half2_rn((acc[i][0] + bias[0]) * d, (acc[i][1] + bias[1]) * d);
            o[1] = __floats2half2_rn((acc[i][2] + bias[2]) * d, (acc[i][3] + bias[3]) * d);
            o[2] = __floats2half2_rn((acc[i][4] + bias[4]) * d, (acc[i][5] + bias[5]) * d);
            o[3] = __floats2half2_rn((acc[i][6] + bias[6]) * d, (acc[i][7] + bias[7]) * d);
            *(uint4*)&outh[gr * 32 + (c0 >> 1)] = *(uint4*)o;
        }
    }
}

// ---------------- fused decode over fp16 z (r4 version: pos scatters via einv) ----------------

__device__ __forceinline__ float dot8h(float4 A, float4 B) {
    union { float4 f; __half2 h[4]; } ua, ub;
    ua.f = A; ub.f = B;
    float s = 0.f;
#pragma unroll
    for (int k = 0; k < 4; ++k) {
        float2 fa = __half22float2(ua.h[k]);
        float2 fb = __half22float2(ub.h[k]);
        s = fmaf(fa.x, fb.x, s);
        s = fmaf(fa.y, fb.y, s);
    }
    return s;
}

__global__ __launch_bounds__(256) void decode16_kernel(const int* __restrict__ rowptr,
                                                       const int* __restrict__ cols,
                                                       const int* __restrict__ einv,
                                                       const int* __restrict__ ne,
                                                       const float4* __restrict__ zf4,
                                                       float* __restrict__ outp,
                                                       int N, int negB, int Ep, int En) {
    const int t = threadIdx.x;
    const int l8 = t & 7;

    if ((int)blockIdx.x < negB) {
        // ----- negative edges: 32 groups x 8 edges per block -----
        const int g = t >> 3;             // 0..31
        const int base = blockIdx.x * 256;
        int a[8], b[8];
        bool v[8];
#pragma unroll
        for (int q = 0; q < 8; ++q) {
            int e = base + q * 32 + g;
            v[q] = e < En;
            a[q] = 0; b[q] = 0;
            if (v[q]) { a[q] = ne[e]; b[q] = ne[En + e]; }
        }
        float4 va[8], vb[8];
#pragma unroll
        for (int q = 0; q < 8; ++q) {
            va[q] = zf4[(size_t)a[q] * 8 + l8];
            vb[q] = zf4[(size_t)b[q] * 8 + l8];
        }
#pragma unroll
        for (int q = 0; q < 8; ++q) {
            float p = dot8h(va[q], vb[q]);
            p += __shfl_xor(p, 4);
            p += __shfl_xor(p, 2);
            p += __shfl_xor(p, 1);
            int e = base + q * 32 + g;
            if (v[q] && l8 == 0) outp[Ep + e] = p;
        }
    } else {
        // ----- positive edges via CSR: scatter final write via einv -----
        int r = (blockIdx.x - negB) * 8 + (t >> 5);
        if (r >= N) return;
        const int l32 = t & 31;
        const int rowbase = t & 32;       // shfl base of this half-wave
        const int g4 = (t >> 3) & 3;      // 0..3 (8-lane group within half-wave)
        int s = rowptr[r], e = rowptr[r + 1];
        if (s == e) return;
        float zr8[8];
        {
            union { float4 f; __half2 h[4]; } uz;
            uz.f = zf4[(size_t)r * 8 + l8];
#pragma unroll
            for (int k = 0; k < 4; ++k) {
                float2 f = __half22float2(uz.h[k]);
                zr8[2 * k] = f.x; zr8[2 * k + 1] = f.y;
            }
        }
        for (int base = s; base < e; base += 32) {
            int n = e - base; if (n > 32) n = 32;
            int idx = (l32 < n) ? cols[base + l32] : 0;
            int ei  = (l32 < n) ? einv[base + l32] : 0;
            for (int j = 0; j < n; j += 8) {
                int pos0 = j + g4, pos1 = j + 4 + g4;
                bool a0 = pos0 < n, a1 = pos1 < n;
                int c0 = __shfl(idx, rowbase + (a0 ? pos0 : 0));
                int c1 = __shfl(idx, rowbase + (a1 ? pos1 : 0));
                // scatter destinations: shfl'd by ALL lanes, never inside the l8 guard
                int d0 = __shfl(ei, rowbase + (a0 ? pos0 : 0));
                int d1 = __shfl(ei, rowbase + (a1 ? pos1 : 0));
                float4 v0 = zf4[(size_t)c0 * 8 + l8];
                float4 v1 = zf4[(size_t)c1 * 8 + l8];
                union { float4 f; __half2 h[4]; } u0, u1;
                u0.f = v0; u1.f = v1;
                float p0 = 0.f, p1 = 0.f;
#pragma unroll
                for (int k = 0; k < 4; ++k) {
                    float2 f0 = __half22float2(u0.h[k]);
                    float2 f1 = __half22float2(u1.h[k]);
                    p0 = fmaf(zr8[2 * k], f0.x, p0); p0 = fmaf(zr8[2 * k + 1], f0.y, p0);
                    p1 = fmaf(zr8[2 * k], f1.x, p1); p1 = fmaf(zr8[2 * k + 1], f1.y, p1);
                }
                p0 += __shfl_xor(p0, 4); p0 += __shfl_xor(p0, 2); p0 += __shfl_xor(p0, 1);
                p1 += __shfl_xor(p1, 4); p1 += __shfl_xor(p1, 2); p1 += __shfl_xor(p1, 1);
                if (l8 == 0) {
                    if (a0) outp[d0] = p0;
                    if (a1) outp[d1] = p1;
                }
            }
        }
    }
}

// ---------------- launch ----------------

extern "C" void kernel_launch(void* const* d_in, const int* in_sizes, int n_in,
                              void* d_out, int out_size, void* d_ws, size_t ws_size,
                              hipStream_t stream) {
    const float* x  = (const float*)d_in[0];
    const int*   pe = (const int*)d_in[1];
    const int*   ne = (const int*)d_in[2];
    const float* W1 = (const float*)d_in[3];
    const float* b1 = (const float*)d_in[4];
    const float* W2 = (const float*)d_in[5];
    const float* b2 = (const float*)d_in[6];
    float* outp = (float*)d_out;

    const int N  = in_sizes[0] / FIN;
    const int Ep = in_sizes[1] / 2;
    const int En = in_sizes[2] / 2;

    char* w = (char*)d_ws;
    size_t off = 0;
    auto alloc = [&](size_t bytes) {
        void* p = w + off;
        off = (off + bytes + 255) & ~(size_t)255;
        return p;
    };
    unsigned* deg   = (unsigned*)alloc((size_t)N * 4);
    float* dis      = (float*)alloc((size_t)N * 4);
    int* rowptr     = (int*)alloc((size_t)(N + 1) * 4);
    int* cursor     = (int*)alloc((size_t)N * 4);
    int* blocksums  = (int*)alloc(((size_t)N / SCAN_BLK + 2) * 4);
    int* colsorted  = (int*)alloc((size_t)Ep * 4);
    int* einv       = (int*)alloc((size_t)Ep * 4);
    __half2* A16    = (__half2*)alloc((size_t)N * 64 * 2);   // h16, then h2_16
    float* B        = (float*)alloc((size_t)N * 64 * 4);     // agg1 fp32, then z16

    const int nscan = (N + SCAN_BLK - 1) / SCAN_BLK;
    const int nEdgeBlocks = (Ep + 255) / 256;

    hipMemsetAsync(deg, 0, (size_t)N * 4, stream);

    // CSR build (pos edges)
    deg_kernel<<<nEdgeBlocks, 256, 0, stream>>>(pe, deg, Ep);
    scan_block_kernel<<<nscan, 256, 0, stream>>>(deg, rowptr, blocksums, N);
    scan_add_kernel<<<(N + 255) / 256, 256, 0, stream>>>(rowptr, cursor, deg, dis,
                                                         blocksums, nscan, N, Ep);
    scatter_edges_kernel<<<nEdgeBlocks * NCHUNK, 256, 0, stream>>>(
        pe, pe + Ep, cursor, colsorted, einv, (float)NCHUNK / (float)N, Ep);
    // layer 1: gemm1 -> h16 (fp16), gather (16-B/lane) -> agg1 fp32
    gemm1_kernel<<<(N + 127) / 128, 256, 0, stream>>>(x, W1, b1, dis, A16, N);
    gather16_kernel<<<(N + 7) / 8, 256, 0, stream>>>(rowptr, colsorted, (const float4*)A16,
                                                     nullptr, B, nullptr, N, 0);
    // layer 2: gemm2 -> h2_16 (fp16, overwrites h16), gather -> z16 (fp16, dis-applied)
    gemm2_kernel<<<(N + 127) / 128, 256, 0, stream>>>(B, dis, W2, b2, A16, N);
    __half2* z16 = (__half2*)B;   // agg1 dead after gemm2
    gather16_kernel<<<(N + 7) / 8, 256, 0, stream>>>(rowptr, colsorted, (const float4*)A16,
                                                     dis, nullptr, z16, N, 1);
    // decode: fused pos (CSR + einv scatter) + neg, fp16 z rows
    const int negB = (En + 255) / 256;
    const int posB = (N + 7) / 8;
    decode16_kernel<<<negB + posB, 256, 0, stream>>>(rowptr, colsorted, einv, ne,
                                                     (const float4*)z16, outp,
                                                     N, negB, Ep, En);
}